// Round 1
// baseline (919.422 us; speedup 1.0000x reference)
//
#include <hip/hip_runtime.h>
#include <hip/hip_bf16.h>
#include <math.h>

// Thread-per-sample: each thread streams its own contiguous 1792B
// (48 float4 dirs + 48 float4 cols + 16 float4 vis) and accumulates
// sum_j clip(dot_j)*vis_j*lc_j plus count(dot_j>0) in registers.
//   color = (albedo * w / count) * sum
// NEW (R2): ray_indices is sorted -> a wave's 64 lanes hold 1-2 distinct
// rays. Previously each lane fired 4 device-scope atomics (2M total) to
// mostly the SAME address -> LLC same-address RMW serialization suspected
// as the 8.7x-off-roofline bottleneck. Now: 6-stage __shfl_up segmented
// inclusive scan over (r,g,b,w); only the last lane of each ray-segment
// issues atomics (~32x fewer, chains per ray ~122 -> ~2-4).
__device__ __forceinline__ void accum_light(
    float nx, float ny, float nz,
    float dx, float dy, float dz,
    float cr, float cg, float cb,
    float v, float& sr, float& sg, float& sb, int& cnt)
{
    const float dot = nx * dx + ny * dy + nz * dz;
    cnt += (dot > 0.0f) ? 1 : 0;
    const float d = fminf(fmaxf(dot, 0.0f), 1.0f);
    const float s = d * v;
    sr = fmaf(s, cr, sr);
    sg = fmaf(s, cg, sg);
    sb = fmaf(s, cb, sb);
}

__global__ __launch_bounds__(256) void shade_kernel(
    const float*  __restrict__ albedos,      // [N,3]
    const float*  __restrict__ normals,      // [N,3]
    const float4* __restrict__ light_dirs,   // [N,48] float4 view of [N,64,3]
    const float4* __restrict__ light_cols,   // [N,48]
    const float4* __restrict__ visibility,   // [N,16] float4 view of [N,64]
    const float*  __restrict__ weights,      // [N]
    const int*    __restrict__ ray_indices,  // [N]
    float* __restrict__ acc,                 // [R*3] rgb accum + [R] weight accum
    int N, int R)
{
    const int b = blockIdx.x * blockDim.x + threadIdx.x;
    // No early return: every lane must participate in the wave scan.
    const int bc = (b < N) ? b : (N - 1);

    const float nx = normals[bc * 3 + 0];
    const float ny = normals[bc * 3 + 1];
    const float nz = normals[bc * 3 + 2];

    const float4* dirs = light_dirs + (size_t)bc * 48;
    const float4* cols = light_cols + (size_t)bc * 48;
    const float4* vis  = visibility + (size_t)bc * 16;

    float sr = 0.f, sg = 0.f, sb = 0.f;
    int cnt = 0;

    #pragma unroll 4
    for (int it = 0; it < 16; ++it) {
        const float4 d0 = dirs[it * 3 + 0];
        const float4 d1 = dirs[it * 3 + 1];
        const float4 d2 = dirs[it * 3 + 2];
        const float4 c0 = cols[it * 3 + 0];
        const float4 c1 = cols[it * 3 + 1];
        const float4 c2 = cols[it * 3 + 2];
        const float4 v  = vis[it];
        // 4 lights packed in 3 float4s: light k uses floats [3k, 3k+2]
        accum_light(nx, ny, nz, d0.x, d0.y, d0.z, c0.x, c0.y, c0.z, v.x, sr, sg, sb, cnt);
        accum_light(nx, ny, nz, d0.w, d1.x, d1.y, c0.w, c1.x, c1.y, v.y, sr, sg, sb, cnt);
        accum_light(nx, ny, nz, d1.z, d1.w, d2.x, c1.z, c1.w, c2.x, v.z, sr, sg, sb, cnt);
        accum_light(nx, ny, nz, d2.y, d2.z, d2.w, c2.y, c2.z, c2.w, v.w, sr, sg, sb, cnt);
    }

    const float w   = weights[bc];
    const float inv = w / (float)(cnt > 0 ? cnt : 1);
    const float ar  = albedos[bc * 3 + 0];
    const float ag  = albedos[bc * 3 + 1];
    const float ab  = albedos[bc * 3 + 2];
    const int   ri  = ray_indices[bc];

    // Per-thread final contribution
    float vr = ar * sr * inv;
    float vg = ag * sg * inv;
    float vb = ab * sb * inv;
    float vw = w;
    if (b >= N) { vr = 0.f; vg = 0.f; vb = 0.f; vw = 0.f; }

    // Segmented inclusive scan across the wave (ri non-decreasing: sorted).
    const int lane = (int)(threadIdx.x & 63);
    #pragma unroll
    for (int d = 1; d < 64; d <<= 1) {
        const int   ru = __shfl_up(ri, d, 64);
        const float r0 = __shfl_up(vr, d, 64);
        const float g0 = __shfl_up(vg, d, 64);
        const float b0 = __shfl_up(vb, d, 64);
        const float w0 = __shfl_up(vw, d, 64);
        if (lane >= d && ru == ri) {
            vr += r0; vg += g0; vb += b0; vw += w0;
        }
    }
    // Leader = last lane of its ray segment: holds the full segment sum.
    const int ri_next = __shfl_down(ri, 1, 64);
    const bool leader = (lane == 63) || (ri_next != ri);

    if (leader) {
        atomicAdd(&acc[ri * 3 + 0], vr);
        atomicAdd(&acc[ri * 3 + 1], vg);
        atomicAdd(&acc[ri * 3 + 2], vb);
        atomicAdd(&acc[R * 3 + ri], vw);
    }
}

__global__ void finalize_kernel(
    const float* __restrict__ acc,   // [R*3] + [R]
    const float* __restrict__ bg,    // [R,3]
    float* __restrict__ out,         // [R,3]
    int R)
{
    const int c = blockIdx.x * blockDim.x + threadIdx.x;
    if (c >= R * 3) return;
    const int r = c / 3;
    const float aw = acc[R * 3 + r];
    const float x = acc[c] + bg[c] * (1.0f - aw);
    float y;
    if (x <= 0.0031308f) {
        y = 12.92f * x;
    } else {
        const float safe = fmaxf(x, 1e-8f);
        y = 1.055f * powf(safe, 1.0f / 2.4f) - 0.055f;
    }
    out[c] = y;
}

extern "C" void kernel_launch(void* const* d_in, const int* in_sizes, int n_in,
                              void* d_out, int out_size, void* d_ws, size_t ws_size,
                              hipStream_t stream) {
    const float* albedos     = (const float*)d_in[0];
    const float* normals     = (const float*)d_in[1];
    const float4* light_dirs = (const float4*)d_in[2];
    const float4* light_cols = (const float4*)d_in[3];
    const float4* visibility = (const float4*)d_in[4];
    const float* bg          = (const float*)d_in[5];
    const float* weights     = (const float*)d_in[6];
    const int*   ray_indices = (const int*)d_in[7];

    const int N = in_sizes[0] / 3;
    const int R = in_sizes[5] / 3;

    float* acc = (float*)d_ws;  // R*3 rgb + R weight accumulators

    hipMemsetAsync(acc, 0, (size_t)(R * 4) * sizeof(float), stream);

    shade_kernel<<<(N + 255) / 256, 256, 0, stream>>>(
        albedos, normals, light_dirs, light_cols, visibility,
        weights, ray_indices, acc, N, R);

    const int fin_threads = R * 3;
    finalize_kernel<<<(fin_threads + 255) / 256, 256, 0, stream>>>(acc, bg, (float*)d_out, R);
}